// Round 1
// baseline (934.731 us; speedup 1.0000x reference)
//
#include <hip/hip_runtime.h>
#include <hip/hip_bf16.h>
#include <stdint.h>

#define HB 12

typedef unsigned short u16;
typedef __bf16 bf16x8 __attribute__((ext_vector_type(8)));
typedef float f32x4 __attribute__((ext_vector_type(4)));
typedef float f4v __attribute__((ext_vector_type(4)));
typedef u16 u16x4 __attribute__((ext_vector_type(4)));
typedef u16 u16x8 __attribute__((ext_vector_type(8)));

__device__ __forceinline__ u16 f2bf(float f) {
  uint32_t u = __builtin_bit_cast(uint32_t, f);
  u += 0x7fffu + ((u >> 16) & 1u);
  return (u16)(u >> 16);
}

__device__ __forceinline__ void gld16(const u16* g, u16* l) {
  __builtin_amdgcn_global_load_lds((const __attribute__((address_space(1))) void*)g,
                                   (__attribute__((address_space(3))) void*)l, 16, 0, 0);
}

__device__ __forceinline__ f32x4 mfma_bf16(bf16x8 a, bf16x8 b, f32x4 c) {
  return __builtin_amdgcn_mfma_f32_16x16x32_bf16(a, b, c, 0, 0, 0);
}

// ---------------- fp32 -> bf16 convert (vectorized) ----------------
__global__ void k_convert(const float* __restrict__ in, u16* __restrict__ out, int n4) {
  int stride = gridDim.x * blockDim.x;
  for (int i = blockIdx.x * blockDim.x + threadIdx.x; i < n4; i += stride) {
    f4v v = ((const f4v*)in)[i];
    u16x4 o;
    o[0] = f2bf(v[0]); o[1] = f2bf(v[1]); o[2] = f2bf(v[2]); o[3] = f2bf(v[3]);
    ((u16x4*)out)[i] = o;
  }
}

// ---------------- fp32 [rows][cols] -> bf16 transpose [cols][rows] ----------------
__global__ void k_transpose(const float* __restrict__ in, u16* __restrict__ out,
                            int rows, int cols) {
  __shared__ float t[32][33];
  int c0 = blockIdx.x * 32, r0 = blockIdx.y * 32;
  int tx = threadIdx.x, ty = threadIdx.y;
  for (int i = ty; i < 32; i += 8)
    t[i][tx] = in[(size_t)(r0 + i) * cols + c0 + tx];
  __syncthreads();
  for (int i = ty; i < 32; i += 8)
    out[(size_t)(c0 + i) * rows + r0 + tx] = f2bf(t[tx][i]);
}

// ---------------- bf16 GEMM: C[M][Nc] = A[M][768] * Bt[Nc][768]^T + bias ----------------
// 128x128 tile, BK=32, 256 threads (4 waves, 2x2), double-buffered LDS via global_load_lds.
// LDS chunk swizzle: 16B chunk c of row r stored at c ^ ((r>>1)&3)  -> 2-way bank aliasing only.
template <int OUTF32>
__global__ void k_gemm(const u16* __restrict__ A, const u16* __restrict__ Bt,
                       const float* __restrict__ bias, void* __restrict__ C, int Nc) {
  const int K = 768;
  __shared__ u16 lA[2][4096], lB[2][4096];
  int tid = threadIdx.x, w = tid >> 6, l = tid & 63;
  int lg = l >> 4, lr = l & 15;
  int wr = w >> 1, wc = w & 1;
  int m0 = blockIdx.y * 128, n0 = blockIdx.x * 128;

  auto stage = [&](int buf, int k0) {
#pragma unroll
    for (int it = 0; it < 2; ++it) {
      int chunk = it * 256 + tid;
      int row = chunk >> 2, c = chunk & 3;
      int cg = (c ^ ((row >> 1) & 3)) * 8;
      gld16(&A[(size_t)(m0 + row) * K + k0 + cg], &lA[buf][chunk * 8]);
      gld16(&Bt[(size_t)(n0 + row) * K + k0 + cg], &lB[buf][chunk * 8]);
    }
  };

  f32x4 acc[4][4] = {};
  stage(0, 0);
  for (int kt = 0; kt < 24; ++kt) {
    __syncthreads();  // staging for kt complete (vmcnt drained) + prior reads done
    if (kt < 23) stage((kt + 1) & 1, (kt + 1) * 32);
    const u16* a = lA[kt & 1];
    const u16* b = lB[kt & 1];
    bf16x8 af[4], bfr[4];
#pragma unroll
    for (int i = 0; i < 4; ++i) {
      int ra = wr * 64 + i * 16 + lr;
      af[i] = *(const bf16x8*)&a[ra * 32 + ((lg ^ ((ra >> 1) & 3)) * 8)];
      int rb = wc * 64 + i * 16 + lr;
      bfr[i] = *(const bf16x8*)&b[rb * 32 + ((lg ^ ((rb >> 1) & 3)) * 8)];
    }
#pragma unroll
    for (int i = 0; i < 4; ++i)
#pragma unroll
      for (int j = 0; j < 4; ++j)
        acc[i][j] = mfma_bf16(af[i], bfr[j], acc[i][j]);
  }
  // epilogue: C/D layout col = lane&15, row = (lane>>4)*4 + reg
#pragma unroll
  for (int j = 0; j < 4; ++j) {
    int col = n0 + wc * 64 + j * 16 + lr;
    float bv = bias[col];
#pragma unroll
    for (int i = 0; i < 4; ++i) {
      int rb = m0 + wr * 64 + i * 16 + lg * 4;
#pragma unroll
      for (int r = 0; r < 4; ++r) {
        float v = acc[i][j][r] + bv;
        if (OUTF32)
          ((float*)C)[(size_t)(rb + r) * Nc + col] = v;
        else
          ((u16*)C)[(size_t)(rb + r) * Nc + col] = f2bf(v);
      }
    }
  }
}

// ---------------- extract V from qkv and transpose to [b*H+h][dv][n] ----------------
__global__ void k_vtrans(const u16* __restrict__ qkv, u16* __restrict__ vt) {
  __shared__ u16 t[64][80];
  int tid = threadIdx.x;
  int n0 = blockIdx.x * 64, bh = blockIdx.y;
  int b = bh / HB, h = bh % HB;
#pragma unroll
  for (int it = 0; it < 2; ++it) {
    int nl = it * 32 + (tid >> 3), dv0 = (tid & 7) * 8;
    u16x8 v = *(const u16x8*)&qkv[(size_t)(b * 1024 + n0 + nl) * 2304 + 1536 + h * 64 + dv0];
    *(u16x8*)&t[nl][dv0] = v;
  }
  __syncthreads();
  int dv = tid >> 2, c = (tid & 3) * 16;
  u16x8 o0, o1;
#pragma unroll
  for (int j = 0; j < 8; ++j) o0[j] = t[c + j][dv];
#pragma unroll
  for (int j = 0; j < 8; ++j) o1[j] = t[c + 8 + j][dv];
  size_t base = (size_t)(bh * 64 + dv) * 1024 + n0 + c;
  *(u16x8*)&vt[base] = o0;
  *(u16x8*)&vt[base + 8] = o1;
}

// ---------------- flash attention: one (qtile=128, b, h) per block; 4 waves x 32 q-rows ----
__global__ __launch_bounds__(256) void k_attn(const u16* __restrict__ qkv,
                                              const u16* __restrict__ vt,
                                              u16* __restrict__ out) {
  __shared__ u16 lP[16384];  // 32KB per-wave P tiles; first 8192 doubles as Q staging
  __shared__ u16 lK[8192];   // [128 n][64 d], swizzled chunks
  __shared__ u16 lV[8192];   // [64 dv][128 n], swizzled chunks
  int tid = threadIdx.x, w = tid >> 6, l = tid & 63;
  int lg = l >> 4, lr = l & 15;
  int qt = blockIdx.x, bh = blockIdx.y;
  int b = bh / HB, h = bh % HB;
  int q0 = qt * 128;

  // stage Q tile [128][64] (swizzled: chunk c of row r stored at c ^ (r&7))
#pragma unroll
  for (int it = 0; it < 4; ++it) {
    int chunk = it * 256 + tid;
    int row = chunk >> 3, c = chunk & 7;
    int cg = (c ^ (row & 7)) * 8;
    gld16(&qkv[(size_t)(b * 1024 + q0 + row) * 2304 + h * 64 + cg], &lP[chunk * 8]);
  }
  __syncthreads();
  // hoist Q fragments to registers
  bf16x8 qf[2][2];
#pragma unroll
  for (int m = 0; m < 2; ++m)
#pragma unroll
    for (int kb = 0; kb < 2; ++kb) {
      int row = w * 32 + m * 16 + lr;
      qf[m][kb] = *(const bf16x8*)&lP[row * 64 + (((kb * 4 + lg) ^ (row & 7)) * 8)];
    }

  f32x4 oacc[2][4] = {};
  float mrun[2][4], lrun[2][4];
#pragma unroll
  for (int m = 0; m < 2; ++m)
#pragma unroll
    for (int j = 0; j < 4; ++j) { mrun[m][j] = -3.0e38f; lrun[m][j] = 0.f; }

  u16* Pw = &lP[w * 4096];
  const float scale = 0.125f;

  for (int kt = 0; kt < 8; ++kt) {
    int n0 = kt * 128;
    __syncthreads();  // prior tile's LDS reads complete (also fences Q hoist at kt=0)
#pragma unroll
    for (int it = 0; it < 4; ++it) {
      int chunk = it * 256 + tid;
      int row = chunk >> 3, c = chunk & 7;
      int cg = (c ^ (row & 7)) * 8;
      gld16(&qkv[(size_t)(b * 1024 + n0 + row) * 2304 + 768 + h * 64 + cg], &lK[chunk * 8]);
    }
#pragma unroll
    for (int it = 0; it < 4; ++it) {
      int chunk = it * 256 + tid;
      int row = chunk >> 4, c = chunk & 15;
      int cg = (c ^ (row & 7)) * 8;
      gld16(&vt[(size_t)(bh * 64 + row) * 1024 + n0 + cg], &lV[chunk * 8]);
    }
    __syncthreads();  // staging complete (vmcnt drained at barrier)

    // S = Q K^T  (A=Q rows q, B=K rows n as cols)
    f32x4 sacc[2][8] = {};
#pragma unroll
    for (int nf = 0; nf < 8; ++nf) {
      int rk = nf * 16 + lr;
      bf16x8 k0 = *(const bf16x8*)&lK[rk * 64 + ((lg ^ (rk & 7)) * 8)];
      bf16x8 k1 = *(const bf16x8*)&lK[rk * 64 + (((4 + lg) ^ (rk & 7)) * 8)];
      sacc[0][nf] = mfma_bf16(qf[0][0], k0, sacc[0][nf]);
      sacc[0][nf] = mfma_bf16(qf[0][1], k1, sacc[0][nf]);
      sacc[1][nf] = mfma_bf16(qf[1][0], k0, sacc[1][nf]);
      sacc[1][nf] = mfma_bf16(qf[1][1], k1, sacc[1][nf]);
    }
    // online softmax: rows = (l>>4)*4 + j (+16m); 16-lane groups share rows
#pragma unroll
    for (int m = 0; m < 2; ++m) {
#pragma unroll
      for (int j = 0; j < 4; ++j) {
        float tmax = -3.0e38f;
#pragma unroll
        for (int nf = 0; nf < 8; ++nf) {
          sacc[m][nf][j] *= scale;
          tmax = fmaxf(tmax, sacc[m][nf][j]);
        }
        tmax = fmaxf(tmax, __shfl_xor(tmax, 1));
        tmax = fmaxf(tmax, __shfl_xor(tmax, 2));
        tmax = fmaxf(tmax, __shfl_xor(tmax, 4));
        tmax = fmaxf(tmax, __shfl_xor(tmax, 8));
        float mnew = fmaxf(mrun[m][j], tmax);
        float corr = __expf(mrun[m][j] - mnew);
        float rsum = 0.f;
#pragma unroll
        for (int nf = 0; nf < 8; ++nf) {
          float p = __expf(sacc[m][nf][j] - mnew);
          sacc[m][nf][j] = p;
          rsum += p;
        }
        rsum += __shfl_xor(rsum, 1);
        rsum += __shfl_xor(rsum, 2);
        rsum += __shfl_xor(rsum, 4);
        rsum += __shfl_xor(rsum, 8);
        lrun[m][j] = lrun[m][j] * corr + rsum;
        mrun[m][j] = mnew;
#pragma unroll
        for (int dvf = 0; dvf < 4; ++dvf) oacc[m][dvf][j] *= corr;
      }
    }
    // P (bf16) -> per-wave LDS, swizzled like a [32][128] tile
#pragma unroll
    for (int m = 0; m < 2; ++m)
#pragma unroll
      for (int nf = 0; nf < 8; ++nf)
#pragma unroll
        for (int j = 0; j < 4; ++j) {
          int row = m * 16 + lg * 4 + j;
          int col = nf * 16 + lr;
          Pw[row * 128 + (((col >> 3) ^ (row & 7)) * 8) + (col & 7)] = f2bf(sacc[m][nf][j]);
        }
    // O += P V
#pragma unroll
    for (int kb2 = 0; kb2 < 4; ++kb2) {
      bf16x8 pf0, pf1;
      {
        int r0r = lr, c = kb2 * 4 + lg;
        pf0 = *(const bf16x8*)&Pw[r0r * 128 + ((c ^ (r0r & 7)) * 8)];
        int r1r = 16 + lr;
        pf1 = *(const bf16x8*)&Pw[r1r * 128 + ((c ^ (r1r & 7)) * 8)];
      }
#pragma unroll
      for (int dvf = 0; dvf < 4; ++dvf) {
        int rv = dvf * 16 + lr, c = kb2 * 4 + lg;
        bf16x8 vf = *(const bf16x8*)&lV[rv * 128 + ((c ^ (rv & 7)) * 8)];
        oacc[0][dvf] = mfma_bf16(pf0, vf, oacc[0][dvf]);
        oacc[1][dvf] = mfma_bf16(pf1, vf, oacc[1][dvf]);
      }
    }
  }
  // normalize + store bf16 into [b][n][h*64+dv]
#pragma unroll
  for (int m = 0; m < 2; ++m)
#pragma unroll
    for (int j = 0; j < 4; ++j) {
      float inv = 1.f / lrun[m][j];
      int q = q0 + w * 32 + m * 16 + lg * 4 + j;
#pragma unroll
      for (int dvf = 0; dvf < 4; ++dvf) {
        int dv = dvf * 16 + lr;
        out[(size_t)(b * 1024 + q) * 768 + h * 64 + dv] = f2bf(oacc[m][dvf][j] * inv);
      }
    }
}

extern "C" void kernel_launch(void* const* d_in, const int* in_sizes, int n_in,
                              void* d_out, int out_size, void* d_ws, size_t ws_size,
                              hipStream_t stream) {
  const float* x      = (const float*)d_in[0];
  const float* w_qkv  = (const float*)d_in[1];
  const float* b_qkv  = (const float*)d_in[2];
  const float* w_proj = (const float*)d_in[3];
  const float* b_proj = (const float*)d_in[4];

  u16* ws = (u16*)d_ws;
  u16* xbf    = ws;                      // 25165824 elems (aliased as attn_o after QKV GEMM)
  u16* attn_o = xbf;
  u16* wqkvT  = ws + 25165824;           // 1769472
  u16* wprojT = wqkvT + 1769472;         // 589824
  u16* qkvb   = wprojT + 589824;         // 75497472
  u16* vtb    = qkvb + 75497472;         // 25165824
  // total ws usage: 256,376,832 bytes

  k_convert<<<2048, 256, 0, stream>>>(x, xbf, 25165824 / 4);
  k_transpose<<<dim3(2304 / 32, 768 / 32), dim3(32, 8), 0, stream>>>(w_qkv, wqkvT, 768, 2304);
  k_transpose<<<dim3(768 / 32, 768 / 32), dim3(32, 8), 0, stream>>>(w_proj, wprojT, 768, 768);
  k_gemm<0><<<dim3(18, 256), 256, 0, stream>>>(xbf, wqkvT, b_qkv, qkvb, 2304);
  k_vtrans<<<dim3(16, 384), 256, 0, stream>>>(qkvb, vtb);
  k_attn<<<dim3(8, 384), 256, 0, stream>>>(qkvb, vtb, attn_o);
  k_gemm<1><<<dim3(6, 256), 256, 0, stream>>>(attn_o, wprojT, b_proj, d_out, 768);
}

// Round 2
// 720.333 us; speedup vs baseline: 1.2976x; 1.2976x over previous
//
#include <hip/hip_runtime.h>
#include <hip/hip_bf16.h>
#include <stdint.h>

#define HB 12

typedef unsigned short u16;
typedef __bf16 bf16x8 __attribute__((ext_vector_type(8)));
typedef float f32x4 __attribute__((ext_vector_type(4)));
typedef float f4v __attribute__((ext_vector_type(4)));
typedef u16 u16x4 __attribute__((ext_vector_type(4)));
typedef u16 u16x8 __attribute__((ext_vector_type(8)));

__device__ __forceinline__ u16 f2bf(float f) {
  uint32_t u = __builtin_bit_cast(uint32_t, f);
  u += 0x7fffu + ((u >> 16) & 1u);
  return (u16)(u >> 16);
}

__device__ __forceinline__ void gld16(const u16* g, u16* l) {
  __builtin_amdgcn_global_load_lds((const __attribute__((address_space(1))) void*)g,
                                   (__attribute__((address_space(3))) void*)l, 16, 0, 0);
}

__device__ __forceinline__ f32x4 mfma_bf16(bf16x8 a, bf16x8 b, f32x4 c) {
  return __builtin_amdgcn_mfma_f32_16x16x32_bf16(a, b, c, 0, 0, 0);
}

// ---------------- fp32 -> bf16 convert (vectorized) ----------------
__global__ void k_convert(const float* __restrict__ in, u16* __restrict__ out, int n4) {
  int stride = gridDim.x * blockDim.x;
  for (int i = blockIdx.x * blockDim.x + threadIdx.x; i < n4; i += stride) {
    f4v v = ((const f4v*)in)[i];
    u16x4 o;
    o[0] = f2bf(v[0]); o[1] = f2bf(v[1]); o[2] = f2bf(v[2]); o[3] = f2bf(v[3]);
    ((u16x4*)out)[i] = o;
  }
}

// ---------------- fp32 [rows][cols] -> bf16 transpose [cols][rows] ----------------
__global__ void k_transpose(const float* __restrict__ in, u16* __restrict__ out,
                            int rows, int cols) {
  __shared__ float t[32][33];
  int c0 = blockIdx.x * 32, r0 = blockIdx.y * 32;
  int tx = threadIdx.x, ty = threadIdx.y;
  for (int i = ty; i < 32; i += 8)
    t[i][tx] = in[(size_t)(r0 + i) * cols + c0 + tx];
  __syncthreads();
  for (int i = ty; i < 32; i += 8)
    out[(size_t)(c0 + i) * rows + r0 + tx] = f2bf(t[tx][i]);
}

// ---------------- bf16 GEMM: C[M][Nc] = A[M][768] * Bt[Nc][768]^T + bias ----------------
// 128x128 tile, BK=32, 4 waves, double-buffered LDS via global_load_lds.
// XCD swizzle: each XCD owns 32 contiguous row-panels (by) for all bx -> A panel L2 reuse.
template <int OUTF32>
__global__ void k_gemm(const u16* __restrict__ A, const u16* __restrict__ Bt,
                       const float* __restrict__ bias, void* __restrict__ C,
                       int Nc, int nx) {
  const int K = 768;
  __shared__ u16 lA[2][4096], lB[2][4096];
  int tid = threadIdx.x, w = tid >> 6, l = tid & 63;
  int lg = l >> 4, lr = l & 15;
  int wr = w >> 1, wc = w & 1;
  int lin = blockIdx.x;
  int xcd = lin & 7, idx = lin >> 3;
  int by = xcd * 32 + idx / nx;
  int bx = idx % nx;
  int m0 = by * 128, n0 = bx * 128;

  auto stage = [&](int buf, int k0) {
#pragma unroll
    for (int it = 0; it < 2; ++it) {
      int chunk = it * 256 + tid;
      int row = chunk >> 2, c = chunk & 3;
      int cg = (c ^ ((row >> 1) & 3)) * 8;
      gld16(&A[(size_t)(m0 + row) * K + k0 + cg], &lA[buf][chunk * 8]);
      gld16(&Bt[(size_t)(n0 + row) * K + k0 + cg], &lB[buf][chunk * 8]);
    }
  };

  f32x4 acc[4][4] = {};
  stage(0, 0);
  for (int kt = 0; kt < 24; ++kt) {
    __syncthreads();  // staging for kt complete (vmcnt drained) + prior reads done
    if (kt < 23) stage((kt + 1) & 1, (kt + 1) * 32);
    const u16* a = lA[kt & 1];
    const u16* b = lB[kt & 1];
    bf16x8 af[4], bfr[4];
#pragma unroll
    for (int i = 0; i < 4; ++i) {
      int ra = wr * 64 + i * 16 + lr;
      af[i] = *(const bf16x8*)&a[ra * 32 + ((lg ^ ((ra >> 1) & 3)) * 8)];
      int rb = wc * 64 + i * 16 + lr;
      bfr[i] = *(const bf16x8*)&b[rb * 32 + ((lg ^ ((rb >> 1) & 3)) * 8)];
    }
    __builtin_amdgcn_s_setprio(1);
#pragma unroll
    for (int i = 0; i < 4; ++i)
#pragma unroll
      for (int j = 0; j < 4; ++j)
        acc[i][j] = mfma_bf16(af[i], bfr[j], acc[i][j]);
    __builtin_amdgcn_s_setprio(0);
  }
  // epilogue: C/D layout col = lane&15, row = (lane>>4)*4 + reg
#pragma unroll
  for (int j = 0; j < 4; ++j) {
    int col = n0 + wc * 64 + j * 16 + lr;
    float bv = bias[col];
#pragma unroll
    for (int i = 0; i < 4; ++i) {
      int rb = m0 + wr * 64 + i * 16 + lg * 4;
#pragma unroll
      for (int r = 0; r < 4; ++r) {
        float v = acc[i][j][r] + bv;
        if (OUTF32)
          ((float*)C)[(size_t)(rb + r) * Nc + col] = v;
        else
          ((u16*)C)[(size_t)(rb + r) * Nc + col] = f2bf(v);
      }
    }
  }
}

// ---------------- extract V from qkv and transpose to [b*H+h][dv][n] ----------------
__global__ void k_vtrans(const u16* __restrict__ qkv, u16* __restrict__ vt) {
  __shared__ u16 t[64][80];
  int tid = threadIdx.x;
  int n0 = blockIdx.x * 64, bh = blockIdx.y;
  int b = bh / HB, h = bh % HB;
#pragma unroll
  for (int it = 0; it < 2; ++it) {
    int nl = it * 32 + (tid >> 3), dv0 = (tid & 7) * 8;
    u16x8 v = *(const u16x8*)&qkv[(size_t)(b * 1024 + n0 + nl) * 2304 + 1536 + h * 64 + dv0];
    *(u16x8*)&t[nl][dv0] = v;
  }
  __syncthreads();
  int dv = tid >> 2, c = (tid & 3) * 16;
  u16x8 o0, o1;
#pragma unroll
  for (int j = 0; j < 8; ++j) o0[j] = t[c + j][dv];
#pragma unroll
  for (int j = 0; j < 8; ++j) o1[j] = t[c + 8 + j][dv];
  size_t base = (size_t)(bh * 64 + dv) * 1024 + n0 + c;
  *(u16x8*)&vt[base] = o0;
  *(u16x8*)&vt[base + 8] = o1;
}

// ---------------- flash attention ----------------
// 1 block = 128 q-rows of one (b,h); 4 waves x 32 rows. KV tile = 64 (16 iters),
// K/V double-buffered (stage kt+1 during compute kt). LDS = 48KB -> 3 blocks/CU.
// XCD swizzle: each XCD owns 48 contiguous bh (all 8 q-tiles) -> K/V L2-resident.
__global__ __launch_bounds__(256) void k_attn(const u16* __restrict__ qkv,
                                              const u16* __restrict__ vt,
                                              u16* __restrict__ out) {
  __shared__ u16 lK[2][4096];  // [64 n][64 d], swizzled 16B chunks
  __shared__ u16 lV[2][4096];  // [64 dv][64 n], swizzled 16B chunks
  __shared__ u16 lP[8192];     // per-wave P [32][64]; doubles as Q staging [128][64]
  int tid = threadIdx.x, w = tid >> 6, l = tid & 63;
  int lg = l >> 4, lr = l & 15;
  int lin = blockIdx.x;
  int xcd = lin & 7, idx = lin >> 3;
  int bh = xcd * 48 + (idx >> 3);
  int qt = idx & 7;
  int b = bh / HB, h = bh % HB;
  int q0 = qt * 128;

  // stage Q tile [128][64] into lP (chunk c of row r stored at c ^ (r&7))
#pragma unroll
  for (int it = 0; it < 4; ++it) {
    int chunk = it * 256 + tid;
    int row = chunk >> 3, c = chunk & 7;
    int cg = (c ^ (row & 7)) * 8;
    gld16(&qkv[(size_t)(b * 1024 + q0 + row) * 2304 + h * 64 + cg], &lP[chunk * 8]);
  }

  auto stage = [&](int buf, int kt) {
    int n0 = kt * 64;
#pragma unroll
    for (int it = 0; it < 2; ++it) {
      int chunk = it * 256 + tid;
      int row = chunk >> 3, c = chunk & 7;
      int cg = (c ^ (row & 7)) * 8;
      gld16(&qkv[(size_t)(b * 1024 + n0 + row) * 2304 + 768 + h * 64 + cg], &lK[buf][chunk * 8]);
      gld16(&vt[(size_t)(bh * 64 + row) * 1024 + n0 + cg], &lV[buf][chunk * 8]);
    }
  };

  stage(0, 0);
  __syncthreads();  // Q + first K/V tile staged (vmcnt drained at barrier)

  // hoist Q fragments to registers (each wave reads only its own lP region)
  bf16x8 qf[2][2];
#pragma unroll
  for (int m = 0; m < 2; ++m)
#pragma unroll
    for (int kb = 0; kb < 2; ++kb) {
      int row = w * 32 + m * 16 + lr;
      qf[m][kb] = *(const bf16x8*)&lP[row * 64 + (((kb * 4 + lg) ^ (row & 7)) * 8)];
    }

  f32x4 oacc[2][4] = {};
  float mrun[2][4], lrun[2][4];
#pragma unroll
  for (int m = 0; m < 2; ++m)
#pragma unroll
    for (int j = 0; j < 4; ++j) { mrun[m][j] = -3.0e38f; lrun[m][j] = 0.f; }

  u16* Pw = &lP[w * 2048];  // per-wave P tile [32][64]
  const float scale = 0.125f;

  for (int kt = 0; kt < 16; ++kt) {
    int cur = kt & 1;
    if (kt < 15) stage(cur ^ 1, kt + 1);  // overlap with compute below
    const u16* Kc = lK[cur];
    const u16* Vc = lV[cur];

    // S = Q K^T
    f32x4 sacc[2][4] = {};
    __builtin_amdgcn_s_setprio(1);
#pragma unroll
    for (int nf = 0; nf < 4; ++nf) {
      int rk = nf * 16 + lr;
      bf16x8 k0 = *(const bf16x8*)&Kc[rk * 64 + ((lg ^ (rk & 7)) * 8)];
      bf16x8 k1 = *(const bf16x8*)&Kc[rk * 64 + (((4 + lg) ^ (rk & 7)) * 8)];
      sacc[0][nf] = mfma_bf16(qf[0][0], k0, sacc[0][nf]);
      sacc[0][nf] = mfma_bf16(qf[0][1], k1, sacc[0][nf]);
      sacc[1][nf] = mfma_bf16(qf[1][0], k0, sacc[1][nf]);
      sacc[1][nf] = mfma_bf16(qf[1][1], k1, sacc[1][nf]);
    }
    __builtin_amdgcn_s_setprio(0);

    // online softmax: row = m*16 + lg*4 + j; n spread over nf (4) x lr (16 lanes)
#pragma unroll
    for (int m = 0; m < 2; ++m) {
#pragma unroll
      for (int j = 0; j < 4; ++j) {
        float tmax = -3.0e38f;
#pragma unroll
        for (int nf = 0; nf < 4; ++nf) {
          sacc[m][nf][j] *= scale;
          tmax = fmaxf(tmax, sacc[m][nf][j]);
        }
        tmax = fmaxf(tmax, __shfl_xor(tmax, 1));
        tmax = fmaxf(tmax, __shfl_xor(tmax, 2));
        tmax = fmaxf(tmax, __shfl_xor(tmax, 4));
        tmax = fmaxf(tmax, __shfl_xor(tmax, 8));
        float mnew = fmaxf(mrun[m][j], tmax);
        float corr = __expf(mrun[m][j] - mnew);
        float rsum = 0.f;
#pragma unroll
        for (int nf = 0; nf < 4; ++nf) {
          float p = __expf(sacc[m][nf][j] - mnew);
          sacc[m][nf][j] = p;
          rsum += p;
        }
        rsum += __shfl_xor(rsum, 1);
        rsum += __shfl_xor(rsum, 2);
        rsum += __shfl_xor(rsum, 4);
        rsum += __shfl_xor(rsum, 8);
        lrun[m][j] = lrun[m][j] * corr + rsum;
        mrun[m][j] = mnew;
#pragma unroll
        for (int dvf = 0; dvf < 4; ++dvf) oacc[m][dvf][j] *= corr;
      }
    }

    // P (bf16) -> per-wave LDS [32][64], swizzled
#pragma unroll
    for (int m = 0; m < 2; ++m)
#pragma unroll
      for (int nf = 0; nf < 4; ++nf)
#pragma unroll
        for (int j = 0; j < 4; ++j) {
          int row = m * 16 + lg * 4 + j;
          int col = nf * 16 + lr;
          Pw[row * 64 + (((col >> 3) ^ (row & 7)) * 8) + (col & 7)] = f2bf(sacc[m][nf][j]);
        }

    // O += P V
    __builtin_amdgcn_s_setprio(1);
#pragma unroll
    for (int kb2 = 0; kb2 < 2; ++kb2) {
      bf16x8 pf0, pf1;
      {
        int c = kb2 * 4 + lg;
        int r0r = lr;
        pf0 = *(const bf16x8*)&Pw[r0r * 64 + ((c ^ (r0r & 7)) * 8)];
        int r1r = 16 + lr;
        pf1 = *(const bf16x8*)&Pw[r1r * 64 + ((c ^ (r1r & 7)) * 8)];
      }
#pragma unroll
      for (int dvf = 0; dvf < 4; ++dvf) {
        int rv = dvf * 16 + lr, c = kb2 * 4 + lg;
        bf16x8 vf = *(const bf16x8*)&Vc[rv * 64 + ((c ^ (rv & 7)) * 8)];
        oacc[0][dvf] = mfma_bf16(pf0, vf, oacc[0][dvf]);
        oacc[1][dvf] = mfma_bf16(pf1, vf, oacc[1][dvf]);
      }
    }
    __builtin_amdgcn_s_setprio(0);

    if (kt < 15) __syncthreads();  // all waves done with buf cur; stage(kt+1) drains here
  }

  // normalize + store bf16 into [b][n][h*64+dv]
#pragma unroll
  for (int m = 0; m < 2; ++m)
#pragma unroll
    for (int j = 0; j < 4; ++j) {
      float inv = 1.f / lrun[m][j];
      int q = q0 + w * 32 + m * 16 + lg * 4 + j;
#pragma unroll
      for (int dvf = 0; dvf < 4; ++dvf) {
        int dv = dvf * 16 + lr;
        out[(size_t)(b * 1024 + q) * 768 + h * 64 + dv] = f2bf(oacc[m][dvf][j] * inv);
      }
    }
}

extern "C" void kernel_launch(void* const* d_in, const int* in_sizes, int n_in,
                              void* d_out, int out_size, void* d_ws, size_t ws_size,
                              hipStream_t stream) {
  const float* x      = (const float*)d_in[0];
  const float* w_qkv  = (const float*)d_in[1];
  const float* b_qkv  = (const float*)d_in[2];
  const float* w_proj = (const float*)d_in[3];
  const float* b_proj = (const float*)d_in[4];

  u16* ws = (u16*)d_ws;
  u16* xbf    = ws;                      // 25165824 elems (aliased as attn_o after QKV GEMM)
  u16* attn_o = xbf;
  u16* wqkvT  = ws + 25165824;           // 1769472
  u16* wprojT = wqkvT + 1769472;         // 589824
  u16* qkvb   = wprojT + 589824;         // 75497472
  u16* vtb    = qkvb + 75497472;         // 25165824
  // total ws usage: 256,376,832 bytes

  k_convert<<<2048, 256, 0, stream>>>(x, xbf, 25165824 / 4);
  k_transpose<<<dim3(2304 / 32, 768 / 32), dim3(32, 8), 0, stream>>>(w_qkv, wqkvT, 768, 2304);
  k_transpose<<<dim3(768 / 32, 768 / 32), dim3(32, 8), 0, stream>>>(w_proj, wprojT, 768, 768);
  k_gemm<0><<<18 * 256, 256, 0, stream>>>(xbf, wqkvT, b_qkv, qkvb, 2304, 18);
  k_vtrans<<<dim3(16, 384), 256, 0, stream>>>(qkvb, vtb);
  k_attn<<<3072, 256, 0, stream>>>(qkvb, vtb, attn_o);
  k_gemm<1><<<6 * 256, 256, 0, stream>>>(attn_o, wprojT, b_proj, d_out, 768, 6);
}

// Round 7
// 584.166 us; speedup vs baseline: 1.6001x; 1.2331x over previous
//
#include <hip/hip_runtime.h>
#include <hip/hip_bf16.h>
#include <stdint.h>

#define HB 12

typedef unsigned short u16;
typedef unsigned int u32;
typedef __bf16 bf16x8 __attribute__((ext_vector_type(8)));
typedef float f32x4 __attribute__((ext_vector_type(4)));
typedef float f32x16 __attribute__((ext_vector_type(16)));
typedef float f4v __attribute__((ext_vector_type(4)));
typedef u16 u16x4 __attribute__((ext_vector_type(4)));
typedef u16 u16x8 __attribute__((ext_vector_type(8)));
typedef u32 u32x2 __attribute__((ext_vector_type(2)));
typedef u32 u32x4v __attribute__((ext_vector_type(4)));

// RTNE f32->bf16 (R1/R2-proven at 4.88e-4).
__device__ __forceinline__ u16 f2bf(float f) {
  uint32_t u = __builtin_bit_cast(uint32_t, f);
  u += 0x7fffu + ((u >> 16) & 1u);
  return (u16)(u >> 16);
}
__device__ __forceinline__ u32 pack2bf(float lo, float hi) {
  return (u32)f2bf(lo) | ((u32)f2bf(hi) << 16);
}

__device__ __forceinline__ void gld16(const u16* g, u16* l) {
  __builtin_amdgcn_global_load_lds((const __attribute__((address_space(1))) void*)g,
                                   (__attribute__((address_space(3))) void*)l, 16, 0, 0);
}

__device__ __forceinline__ f32x4 mfma_bf16(bf16x8 a, bf16x8 b, f32x4 c) {
  return __builtin_amdgcn_mfma_f32_16x16x32_bf16(a, b, c, 0, 0, 0);
}
__device__ __forceinline__ f32x16 mfma32(bf16x8 a, bf16x8 b, f32x16 c) {
  return __builtin_amdgcn_mfma_f32_32x32x16_bf16(a, b, c, 0, 0, 0);
}

// ---------------- fp32 -> bf16 convert (vectorized) ----------------
__global__ void k_convert(const float* __restrict__ in, u16* __restrict__ out, int n4) {
  int stride = gridDim.x * blockDim.x;
  for (int i = blockIdx.x * blockDim.x + threadIdx.x; i < n4; i += stride) {
    f4v v = ((const f4v*)in)[i];
    u16x4 o;
    o[0] = f2bf(v[0]); o[1] = f2bf(v[1]); o[2] = f2bf(v[2]); o[3] = f2bf(v[3]);
    ((u16x4*)out)[i] = o;
  }
}

// ---------------- fp32 [rows][cols] -> bf16 transpose [cols][rows] ----------------
__global__ void k_transpose(const float* __restrict__ in, u16* __restrict__ out,
                            int rows, int cols) {
  __shared__ float t[32][33];
  int c0 = blockIdx.x * 32, r0 = blockIdx.y * 32;
  int tx = threadIdx.x, ty = threadIdx.y;
  for (int i = ty; i < 32; i += 8)
    t[i][tx] = in[(size_t)(r0 + i) * cols + c0 + tx];
  __syncthreads();
  for (int i = ty; i < 32; i += 8)
    out[(size_t)(c0 + i) * rows + r0 + tx] = f2bf(t[tx][i]);
}

// ---------------- bf16 GEMM: C[M][Nc] = A[M][768] * Bt[Nc][768]^T + bias ----------------
template <int OUTF32>
__global__ void k_gemm(const u16* __restrict__ A, const u16* __restrict__ Bt,
                       const float* __restrict__ bias, void* __restrict__ C,
                       int Nc, int nx) {
  const int K = 768;
  __shared__ u16 lA[2][4096], lB[2][4096];
  int tid = threadIdx.x, w = tid >> 6, l = tid & 63;
  int lg = l >> 4, lr = l & 15;
  int wr = w >> 1, wc = w & 1;
  int lin = blockIdx.x;
  int xcd = lin & 7, idx = lin >> 3;
  int by = xcd * 32 + idx / nx;
  int bx = idx % nx;
  int m0 = by * 128, n0 = bx * 128;

  auto stage = [&](int buf, int k0) {
#pragma unroll
    for (int it = 0; it < 2; ++it) {
      int chunk = it * 256 + tid;
      int row = chunk >> 2, c = chunk & 3;
      int cg = (c ^ ((row >> 1) & 3)) * 8;
      gld16(&A[(size_t)(m0 + row) * K + k0 + cg], &lA[buf][chunk * 8]);
      gld16(&Bt[(size_t)(n0 + row) * K + k0 + cg], &lB[buf][chunk * 8]);
    }
  };

  f32x4 acc[4][4] = {};
  stage(0, 0);
  for (int kt = 0; kt < 24; ++kt) {
    __syncthreads();
    if (kt < 23) stage((kt + 1) & 1, (kt + 1) * 32);
    const u16* a = lA[kt & 1];
    const u16* b = lB[kt & 1];
    bf16x8 af[4], bfr[4];
#pragma unroll
    for (int i = 0; i < 4; ++i) {
      int ra = wr * 64 + i * 16 + lr;
      af[i] = *(const bf16x8*)&a[ra * 32 + ((lg ^ ((ra >> 1) & 3)) * 8)];
      int rb = wc * 64 + i * 16 + lr;
      bfr[i] = *(const bf16x8*)&b[rb * 32 + ((lg ^ ((rb >> 1) & 3)) * 8)];
    }
    __builtin_amdgcn_s_setprio(1);
#pragma unroll
    for (int i = 0; i < 4; ++i)
#pragma unroll
      for (int j = 0; j < 4; ++j)
        acc[i][j] = mfma_bf16(af[i], bfr[j], acc[i][j]);
    __builtin_amdgcn_s_setprio(0);
  }
#pragma unroll
  for (int j = 0; j < 4; ++j) {
    int col = n0 + wc * 64 + j * 16 + lr;
    float bv = bias[col];
#pragma unroll
    for (int i = 0; i < 4; ++i) {
      int rb = m0 + wr * 64 + i * 16 + lg * 4;
#pragma unroll
      for (int r = 0; r < 4; ++r) {
        float v = acc[i][j][r] + bv;
        if (OUTF32)
          ((float*)C)[(size_t)(rb + r) * Nc + col] = v;
        else
          ((u16*)C)[(size_t)(rb + r) * Nc + col] = f2bf(v);
      }
    }
  }
}

// ---------------- extract V from qkv and transpose to [b*H+h][dv][n] ----------------
__global__ void k_vtrans(const u16* __restrict__ qkv, u16* __restrict__ vt) {
  __shared__ u16 t[64][80];
  int tid = threadIdx.x;
  int n0 = blockIdx.x * 64, bh = blockIdx.y;
  int b = bh / HB, h = bh % HB;
#pragma unroll
  for (int it = 0; it < 2; ++it) {
    int nl = it * 32 + (tid >> 3), dv0 = (tid & 7) * 8;
    u16x8 v = *(const u16x8*)&qkv[(size_t)(b * 1024 + n0 + nl) * 2304 + 1536 + h * 64 + dv0];
    *(u16x8*)&t[nl][dv0] = v;
  }
  __syncthreads();
  int dv = tid >> 2, c = (tid & 3) * 16;
  u16x8 o0, o1;
#pragma unroll
  for (int j = 0; j < 8; ++j) o0[j] = t[c + j][dv];
#pragma unroll
  for (int j = 0; j < 8; ++j) o1[j] = t[c + 8 + j][dv];
  size_t base = (size_t)(bh * 64 + dv) * 1024 + n0 + c;
  *(u16x8*)&vt[base] = o0;
  *(u16x8*)&vt[base + 8] = o1;
}

// ---------------- flash attention, 32x32 swapped-operand structure ----------------
// BISECT BUILD (R7): same structure as R5/R6 but every unproven primitive
// replaced by an R2-proven one:
//   - permlane32_swap asm  -> __shfl_xor(.,32)
//   - exp2-fold + defer-max -> exact *0.125f, __expf, always-rescale (R2 form)
//   - RTNE pack everywhere
// If this passes: reintroduce permlane/exp2/defer-max one at a time (A/B).
// If this fails: 32x32 path refuted empirically -> revert to R2 kernel.
__global__ __launch_bounds__(256, 4) void k_attn(const u16* __restrict__ qkv,
                                                 const u16* __restrict__ vt,
                                                 u16* __restrict__ out) {
  __shared__ u16 lK[2][4096];  // [64 n][64 d], content chunk-swizzled c^(row&7)
  __shared__ u16 lV[2][4096];  // [64 d][64 n], content chunk-swizzled
  int tid = threadIdx.x, w = tid >> 6, l = tid & 63;
  int q32 = l & 31, hi = l >> 5;
  int lin = blockIdx.x;
  int xcd = lin & 7, idx = lin >> 3;
  int bh = xcd * 48 + (idx >> 3);
  int qt = idx & 7;
  int b = bh / HB, h = bh % HB;
  int qg = qt * 128 + w * 32 + q32;

  // Q fragments (B-operand): col q = l&31, k-elems d = ds*16 + hi*8 .. +8
  bf16x8 qf[4];
  {
    const u16* qrow = &qkv[(size_t)(b * 1024 + qg) * 2304 + h * 64 + hi * 8];
#pragma unroll
    for (int ds = 0; ds < 4; ++ds) qf[ds] = *(const bf16x8*)&qrow[ds * 16];
  }

  auto stage = [&](int buf, int kt) {
    int n0 = kt * 64;
#pragma unroll
    for (int it = 0; it < 2; ++it) {
      int chunk = it * 256 + tid;
      int row = chunk >> 3, c = chunk & 7;
      int cg = (c ^ (row & 7)) * 8;
      gld16(&qkv[(size_t)(b * 1024 + n0 + row) * 2304 + 768 + h * 64 + cg], &lK[buf][chunk * 8]);
      gld16(&vt[(size_t)(bh * 64 + row) * 1024 + n0 + cg], &lV[buf][chunk * 8]);
    }
  };

  stage(0, 0);
  __syncthreads();

  f32x16 oacc[2] = {};
  float mrun = -3.0e38f, lrun = 0.f;

  for (int kt = 0; kt < 16; ++kt) {
    int cur = kt & 1;
    if (kt < 15) stage(cur ^ 1, kt + 1);
    const u16* Kc = lK[cur];
    const u16* Vc = lV[cur];

    // S^T = K Q^T : per lane col q, rows n (in-lane)
    f32x16 s0 = {}, s1 = {};
    __builtin_amdgcn_s_setprio(1);
#pragma unroll
    for (int ds = 0; ds < 4; ++ds) {
      int dchunk = ds * 2 + hi;
      int r0 = q32;
      bf16x8 k0 = *(const bf16x8*)&Kc[r0 * 64 + ((dchunk ^ (r0 & 7)) * 8)];
      int r1 = 32 + q32;
      bf16x8 k1 = *(const bf16x8*)&Kc[r1 * 64 + ((dchunk ^ (r1 & 7)) * 8)];
      s0 = mfma32(k0, qf[ds], s0);
      s1 = mfma32(k1, qf[ds], s1);
    }
    __builtin_amdgcn_s_setprio(0);

    // scale (exact pow2) + in-lane max + pair max via shfl_xor(32)
    float tmax = -3.0e38f;
#pragma unroll
    for (int r = 0; r < 16; ++r) { s0[r] *= 0.125f; tmax = fmaxf(tmax, s0[r]); }
#pragma unroll
    for (int r = 0; r < 16; ++r) { s1[r] *= 0.125f; tmax = fmaxf(tmax, s1[r]); }
    tmax = fmaxf(tmax, __shfl_xor(tmax, 32));

    // R2-exact online softmax (always rescale)
    float mnew = fmaxf(mrun, tmax);
    float corr = __expf(mrun - mnew);
    lrun *= corr;
#pragma unroll
    for (int r = 0; r < 16; ++r) { oacc[0][r] *= corr; oacc[1][r] *= corr; }
    mrun = mnew;

    float rsum = 0.f;
#pragma unroll
    for (int r = 0; r < 16; ++r) { float p = __expf(s0[r] - mnew); s0[r] = p; rsum += p; }
#pragma unroll
    for (int r = 0; r < 16; ++r) { float p = __expf(s1[r] - mnew); s1[r] = p; rsum += p; }
    lrun += rsum + __shfl_xor(rsum, 32);

    // P^T -> B-frags via RTNE pack + shfl_xor(32) routing; PV: O^T += V^T P^T
    // Lane (hi) holds C-regs n = 16ns + (t&3) + 8(t>>2) + 4hi (t = reg within half).
    // Frag word Wp needs n-pair 16ns + 8hi + {2p,2p+1}:
    //   W0 = hi ? partner(a2) : a0    W1 = hi ? partner(a3) : a1
    //   W2 = hi ? a2 : partner(a0)    W3 = hi ? a3 : partner(a1)
    __builtin_amdgcn_s_setprio(1);
#pragma unroll
    for (int half = 0; half < 2; ++half) {
      const f32x16& pv = half ? s1 : s0;
#pragma unroll
      for (int u = 0; u < 2; ++u) {
        int ns = half * 2 + u;
        u32 a0 = pack2bf(pv[8 * u + 0], pv[8 * u + 1]);
        u32 a1 = pack2bf(pv[8 * u + 2], pv[8 * u + 3]);
        u32 a2 = pack2bf(pv[8 * u + 4], pv[8 * u + 5]);
        u32 a3 = pack2bf(pv[8 * u + 6], pv[8 * u + 7]);
        u32 pa0 = (u32)__shfl_xor((int)a0, 32);
        u32 pa1 = (u32)__shfl_xor((int)a1, 32);
        u32 pa2 = (u32)__shfl_xor((int)a2, 32);
        u32 pa3 = (u32)__shfl_xor((int)a3, 32);
        u32x4v pw;
        pw[0] = hi ? pa2 : a0;
        pw[1] = hi ? pa3 : a1;
        pw[2] = hi ? a2 : pa0;
        pw[3] = hi ? a3 : pa1;
        bf16x8 pfrag = __builtin_bit_cast(bf16x8, pw);
        int nchunk = ns * 2 + hi;
#pragma unroll
        for (int dt = 0; dt < 2; ++dt) {
          int rv = dt * 32 + q32;
          bf16x8 vf = *(const bf16x8*)&Vc[rv * 64 + ((nchunk ^ (rv & 7)) * 8)];
          oacc[dt] = mfma32(vf, pfrag, oacc[dt]);
        }
      }
    }
    __builtin_amdgcn_s_setprio(0);

    if (kt < 15) __syncthreads();
  }

  // normalize + store: lane holds O^T[d][q]: d = 32dt + 8g + 4hi + e, q = qg
  float inv = 1.0f / lrun;
  u16* orow = &out[(size_t)(b * 1024 + qg) * 768 + h * 64 + hi * 4];
#pragma unroll
  for (int dt = 0; dt < 2; ++dt)
#pragma unroll
    for (int g = 0; g < 4; ++g) {
      u32 wa = pack2bf(oacc[dt][4 * g + 0] * inv, oacc[dt][4 * g + 1] * inv);
      u32 wb = pack2bf(oacc[dt][4 * g + 2] * inv, oacc[dt][4 * g + 3] * inv);
      u32x2 pr; pr[0] = wa; pr[1] = wb;
      *(u32x2*)&orow[dt * 32 + g * 8] = pr;
    }
}

extern "C" void kernel_launch(void* const* d_in, const int* in_sizes, int n_in,
                              void* d_out, int out_size, void* d_ws, size_t ws_size,
                              hipStream_t stream) {
  const float* x      = (const float*)d_in[0];
  const float* w_qkv  = (const float*)d_in[1];
  const float* b_qkv  = (const float*)d_in[2];
  const float* w_proj = (const float*)d_in[3];
  const float* b_proj = (const float*)d_in[4];

  u16* ws = (u16*)d_ws;
  u16* xbf    = ws;                      // 25165824 elems (aliased as attn_o after QKV GEMM)
  u16* attn_o = xbf;
  u16* wqkvT  = ws + 25165824;           // 1769472
  u16* wprojT = wqkvT + 1769472;         // 589824
  u16* qkvb   = wprojT + 589824;         // 75497472
  u16* vtb    = qkvb + 75497472;         // 25165824

  k_convert<<<2048, 256, 0, stream>>>(x, xbf, 25165824 / 4);
  k_transpose<<<dim3(2304 / 32, 768 / 32), dim3(32, 8), 0, stream>>>(w_qkv, wqkvT, 768, 2304);
  k_transpose<<<dim3(768 / 32, 768 / 32), dim3(32, 8), 0, stream>>>(w_proj, wprojT, 768, 768);
  k_gemm<0><<<18 * 256, 256, 0, stream>>>(xbf, wqkvT, b_qkv, qkvb, 2304, 18);
  k_vtrans<<<dim3(16, 384), 256, 0, stream>>>(qkvb, vtb);
  k_attn<<<3072, 256, 0, stream>>>(qkvb, vtb, attn_o);
  k_gemm<1><<<6 * 256, 256, 0, stream>>>(attn_o, wprojT, b_proj, d_out, 768, 6);
}

// Round 8
// 581.279 us; speedup vs baseline: 1.6081x; 1.0050x over previous
//
#include <hip/hip_runtime.h>
#include <hip/hip_bf16.h>
#include <stdint.h>

#define HB 12

typedef unsigned short u16;
typedef unsigned int u32;
typedef __bf16 bf16x8 __attribute__((ext_vector_type(8)));
typedef float f32x4 __attribute__((ext_vector_type(4)));
typedef float f32x16 __attribute__((ext_vector_type(16)));
typedef float f4v __attribute__((ext_vector_type(4)));
typedef u16 u16x4 __attribute__((ext_vector_type(4)));
typedef u16 u16x8 __attribute__((ext_vector_type(8)));
typedef u32 u32x2 __attribute__((ext_vector_type(2)));
typedef u32 u32x4v __attribute__((ext_vector_type(4)));

// RTNE f32->bf16 (R1/R2/R7-proven).
__device__ __forceinline__ u16 f2bf(float f) {
  uint32_t u = __builtin_bit_cast(uint32_t, f);
  u += 0x7fffu + ((u >> 16) & 1u);
  return (u16)(u >> 16);
}
__device__ __forceinline__ u32 pack2bf(float lo, float hi) {
  return (u32)f2bf(lo) | ((u32)f2bf(hi) << 16);
}
// HW packed f32->bf16 (RNE per MODE default; verified usage m214v22/m240).
__device__ __forceinline__ u32 cvtpk(float lo, float hi) {
  u32 r;
  asm("v_cvt_pk_bf16_f32 %0, %1, %2" : "=v"(r) : "v"(lo), "v"(hi));
  return r;
}

__device__ __forceinline__ void gld16(const u16* g, u16* l) {
  __builtin_amdgcn_global_load_lds((const __attribute__((address_space(1))) void*)g,
                                   (__attribute__((address_space(3))) void*)l, 16, 0, 0);
}

__device__ __forceinline__ f32x4 mfma_bf16(bf16x8 a, bf16x8 b, f32x4 c) {
  return __builtin_amdgcn_mfma_f32_16x16x32_bf16(a, b, c, 0, 0, 0);
}
__device__ __forceinline__ f32x16 mfma32(bf16x8 a, bf16x8 b, f32x16 c) {
  return __builtin_amdgcn_mfma_f32_32x32x16_bf16(a, b, c, 0, 0, 0);
}

// ---------------- fp32 -> bf16 convert (vectorized) ----------------
__global__ void k_convert(const float* __restrict__ in, u16* __restrict__ out, int n4) {
  int stride = gridDim.x * blockDim.x;
  for (int i = blockIdx.x * blockDim.x + threadIdx.x; i < n4; i += stride) {
    f4v v = ((const f4v*)in)[i];
    u16x4 o;
    o[0] = f2bf(v[0]); o[1] = f2bf(v[1]); o[2] = f2bf(v[2]); o[3] = f2bf(v[3]);
    ((u16x4*)out)[i] = o;
  }
}

// ---------------- fp32 [rows][cols] -> bf16 transpose [cols][rows] ----------------
__global__ void k_transpose(const float* __restrict__ in, u16* __restrict__ out,
                            int rows, int cols) {
  __shared__ float t[32][33];
  int c0 = blockIdx.x * 32, r0 = blockIdx.y * 32;
  int tx = threadIdx.x, ty = threadIdx.y;
  for (int i = ty; i < 32; i += 8)
    t[i][tx] = in[(size_t)(r0 + i) * cols + c0 + tx];
  __syncthreads();
  for (int i = ty; i < 32; i += 8)
    out[(size_t)(c0 + i) * rows + r0 + tx] = f2bf(t[tx][i]);
}

// ---------------- bf16 GEMM: C[M][Nc] = A[M][768] * Bt[Nc][768]^T + bias ----------------
template <int OUTF32>
__global__ void k_gemm(const u16* __restrict__ A, const u16* __restrict__ Bt,
                       const float* __restrict__ bias, void* __restrict__ C,
                       int Nc, int nx) {
  const int K = 768;
  __shared__ u16 lA[2][4096], lB[2][4096];
  int tid = threadIdx.x, w = tid >> 6, l = tid & 63;
  int lg = l >> 4, lr = l & 15;
  int wr = w >> 1, wc = w & 1;
  int lin = blockIdx.x;
  int xcd = lin & 7, idx = lin >> 3;
  int by = xcd * 32 + idx / nx;
  int bx = idx % nx;
  int m0 = by * 128, n0 = bx * 128;

  auto stage = [&](int buf, int k0) {
#pragma unroll
    for (int it = 0; it < 2; ++it) {
      int chunk = it * 256 + tid;
      int row = chunk >> 2, c = chunk & 3;
      int cg = (c ^ ((row >> 1) & 3)) * 8;
      gld16(&A[(size_t)(m0 + row) * K + k0 + cg], &lA[buf][chunk * 8]);
      gld16(&Bt[(size_t)(n0 + row) * K + k0 + cg], &lB[buf][chunk * 8]);
    }
  };

  f32x4 acc[4][4] = {};
  stage(0, 0);
  for (int kt = 0; kt < 24; ++kt) {
    __syncthreads();
    if (kt < 23) stage((kt + 1) & 1, (kt + 1) * 32);
    const u16* a = lA[kt & 1];
    const u16* b = lB[kt & 1];
    bf16x8 af[4], bfr[4];
#pragma unroll
    for (int i = 0; i < 4; ++i) {
      int ra = wr * 64 + i * 16 + lr;
      af[i] = *(const bf16x8*)&a[ra * 32 + ((lg ^ ((ra >> 1) & 3)) * 8)];
      int rb = wc * 64 + i * 16 + lr;
      bfr[i] = *(const bf16x8*)&b[rb * 32 + ((lg ^ ((rb >> 1) & 3)) * 8)];
    }
    __builtin_amdgcn_s_setprio(1);
#pragma unroll
    for (int i = 0; i < 4; ++i)
#pragma unroll
      for (int j = 0; j < 4; ++j)
        acc[i][j] = mfma_bf16(af[i], bfr[j], acc[i][j]);
    __builtin_amdgcn_s_setprio(0);
  }
#pragma unroll
  for (int j = 0; j < 4; ++j) {
    int col = n0 + wc * 64 + j * 16 + lr;
    float bv = bias[col];
#pragma unroll
    for (int i = 0; i < 4; ++i) {
      int rb = m0 + wr * 64 + i * 16 + lg * 4;
#pragma unroll
      for (int r = 0; r < 4; ++r) {
        float v = acc[i][j][r] + bv;
        if (OUTF32)
          ((float*)C)[(size_t)(rb + r) * Nc + col] = v;
        else
          ((u16*)C)[(size_t)(rb + r) * Nc + col] = f2bf(v);
      }
    }
  }
}

// ---------------- extract V from qkv and transpose to [b*H+h][dv][n] ----------------
__global__ void k_vtrans(const u16* __restrict__ qkv, u16* __restrict__ vt) {
  __shared__ u16 t[64][80];
  int tid = threadIdx.x;
  int n0 = blockIdx.x * 64, bh = blockIdx.y;
  int b = bh / HB, h = bh % HB;
#pragma unroll
  for (int it = 0; it < 2; ++it) {
    int nl = it * 32 + (tid >> 3), dv0 = (tid & 7) * 8;
    u16x8 v = *(const u16x8*)&qkv[(size_t)(b * 1024 + n0 + nl) * 2304 + 1536 + h * 64 + dv0];
    *(u16x8*)&t[nl][dv0] = v;
  }
  __syncthreads();
  int dv = tid >> 2, c = (tid & 3) * 16;
  u16x8 o0, o1;
#pragma unroll
  for (int j = 0; j < 8; ++j) o0[j] = t[c + j][dv];
#pragma unroll
  for (int j = 0; j < 8; ++j) o1[j] = t[c + 8 + j][dv];
  size_t base = (size_t)(bh * 64 + dv) * 1024 + n0 + c;
  *(u16x8*)&vt[base] = o0;
  *(u16x8*)&vt[base + 8] = o1;
}

// ---------------- flash attention, 32x32 swapped-operand structure ----------------
// R8 = R7 (passed, 195us) + three VALU cuts, routing untouched:
//   1. P-pack: pack2bf (7 ops) -> v_cvt_pk_bf16_f32 (1 op)  [HW RNE]
//   2. exp2-domain softmax, scale folded into fma; EXACT skip-rescale
//   3. P-routing: 4 shfl -> 2 shfl via pre-selected exchange
// shfl_xor(.,32) cross-half routing is the R7-proven form (no permlane asm).
__global__ __launch_bounds__(256, 4) void k_attn(const u16* __restrict__ qkv,
                                                 const u16* __restrict__ vt,
                                                 u16* __restrict__ out) {
  __shared__ u16 lK[2][4096];  // [64 n][64 d], content chunk-swizzled c^(row&7)
  __shared__ u16 lV[2][4096];  // [64 d][64 n], content chunk-swizzled
  int tid = threadIdx.x, w = tid >> 6, l = tid & 63;
  int q32 = l & 31, hi = l >> 5;
  int lin = blockIdx.x;
  int xcd = lin & 7, idx = lin >> 3;
  int bh = xcd * 48 + (idx >> 3);
  int qt = idx & 7;
  int b = bh / HB, h = bh % HB;
  int qg = qt * 128 + w * 32 + q32;

  // Q fragments (B-operand): col q = l&31, k-elems d = ds*16 + hi*8 .. +8
  bf16x8 qf[4];
  {
    const u16* qrow = &qkv[(size_t)(b * 1024 + qg) * 2304 + h * 64 + hi * 8];
#pragma unroll
    for (int ds = 0; ds < 4; ++ds) qf[ds] = *(const bf16x8*)&qrow[ds * 16];
  }

  auto stage = [&](int buf, int kt) {
    int n0 = kt * 64;
#pragma unroll
    for (int it = 0; it < 2; ++it) {
      int chunk = it * 256 + tid;
      int row = chunk >> 3, c = chunk & 7;
      int cg = (c ^ (row & 7)) * 8;
      gld16(&qkv[(size_t)(b * 1024 + n0 + row) * 2304 + 768 + h * 64 + cg], &lK[buf][chunk * 8]);
      gld16(&vt[(size_t)(bh * 64 + row) * 1024 + n0 + cg], &lV[buf][chunk * 8]);
    }
  };

  stage(0, 0);
  __syncthreads();

  f32x16 oacc[2] = {};
  // softmax state in RAW-logit domain; p = exp2(s*cl2 - mc), mc = mrun*cl2
  float mrun = -3.0e38f, lrun = 0.f, mc = -3.0e38f * 0.18033688f;
  const float cl2 = 0.18033688f;  // 0.125 * log2(e)

  for (int kt = 0; kt < 16; ++kt) {
    int cur = kt & 1;
    if (kt < 15) stage(cur ^ 1, kt + 1);
    const u16* Kc = lK[cur];
    const u16* Vc = lV[cur];

    // S^T = K Q^T : per lane col q, rows n (in-lane), RAW (unscaled)
    f32x16 s0 = {}, s1 = {};
    __builtin_amdgcn_s_setprio(1);
#pragma unroll
    for (int ds = 0; ds < 4; ++ds) {
      int dchunk = ds * 2 + hi;
      int r0 = q32;
      bf16x8 k0 = *(const bf16x8*)&Kc[r0 * 64 + ((dchunk ^ (r0 & 7)) * 8)];
      int r1 = 32 + q32;
      bf16x8 k1 = *(const bf16x8*)&Kc[r1 * 64 + ((dchunk ^ (r1 & 7)) * 8)];
      s0 = mfma32(k0, qf[ds], s0);
      s1 = mfma32(k1, qf[ds], s1);
    }
    __builtin_amdgcn_s_setprio(0);

    // in-lane max + pair max via shfl_xor(32)   (raw-logit domain)
    float tmax = s0[0];
#pragma unroll
    for (int r = 1; r < 16; ++r) tmax = fmaxf(tmax, s0[r]);
#pragma unroll
    for (int r = 0; r < 16; ++r) tmax = fmaxf(tmax, s1[r]);
    tmax = fmaxf(tmax, __shfl_xor(tmax, 32));

    // EXACT skip-rescale: skipped only when ALL lanes have tmax <= mrun,
    // in which case corr == exp2(0) == 1 exactly.
    if (__any(tmax > mrun)) {
      float mnew = fmaxf(mrun, tmax);
      float corr = exp2f((mrun - mnew) * cl2);
      lrun *= corr;
#pragma unroll
      for (int r = 0; r < 16; ++r) { oacc[0][r] *= corr; oacc[1][r] *= corr; }
      mrun = mnew;
      mc = mrun * cl2;
    }

    // p = exp2(fma(s, cl2, -mc)), in place; row-sum
    float rsum = 0.f;
#pragma unroll
    for (int r = 0; r < 16; ++r) {
      float p = exp2f(__builtin_fmaf(s0[r], cl2, -mc)); s0[r] = p; rsum += p;
    }
#pragma unroll
    for (int r = 0; r < 16; ++r) {
      float p = exp2f(__builtin_fmaf(s1[r], cl2, -mc)); s1[r] = p; rsum += p;
    }
    lrun += rsum + __shfl_xor(rsum, 32);

    // P^T -> B-frags via cvt_pk + 2-shfl routing; PV: O^T += V^T P^T
    // hi=0 lanes need partner's {a0,a1}; hi=1 lanes need partner's {a2,a3}:
    //   q0 = shfl_xor(hi ? a0 : a2)  -> hi=0: pa0, hi=1: pa2
    //   q1 = shfl_xor(hi ? a1 : a3)  -> hi=0: pa1, hi=1: pa3
    // words: {hi?q0:a0, hi?q1:a1, hi?a2:q0, hi?a3:q1}   (R7-verified mapping)
    __builtin_amdgcn_s_setprio(1);
#pragma unroll
    for (int half = 0; half < 2; ++half) {
      const f32x16& pv = half ? s1 : s0;
#pragma unroll
      for (int u = 0; u < 2; ++u) {
        int ns = half * 2 + u;
        u32 a0 = cvtpk(pv[8 * u + 0], pv[8 * u + 1]);
        u32 a1 = cvtpk(pv[8 * u + 2], pv[8 * u + 3]);
        u32 a2 = cvtpk(pv[8 * u + 4], pv[8 * u + 5]);
        u32 a3 = cvtpk(pv[8 * u + 6], pv[8 * u + 7]);
        u32 q0v = (u32)__shfl_xor((int)(hi ? a0 : a2), 32);
        u32 q1v = (u32)__shfl_xor((int)(hi ? a1 : a3), 32);
        u32x4v pw;
        pw[0] = hi ? q0v : a0;
        pw[1] = hi ? q1v : a1;
        pw[2] = hi ? a2 : q0v;
        pw[3] = hi ? a3 : q1v;
        bf16x8 pfrag = __builtin_bit_cast(bf16x8, pw);
        int nchunk = ns * 2 + hi;
#pragma unroll
        for (int dt = 0; dt < 2; ++dt) {
          int rv = dt * 32 + q32;
          bf16x8 vf = *(const bf16x8*)&Vc[rv * 64 + ((nchunk ^ (rv & 7)) * 8)];
          oacc[dt] = mfma32(vf, pfrag, oacc[dt]);
        }
      }
    }
    __builtin_amdgcn_s_setprio(0);

    if (kt < 15) __syncthreads();
  }

  // normalize + store: lane holds O^T[d][q]: d = 32dt + 8g + 4hi + e, q = qg
  float inv = 1.0f / lrun;
  u16* orow = &out[(size_t)(b * 1024 + qg) * 768 + h * 64 + hi * 4];
#pragma unroll
  for (int dt = 0; dt < 2; ++dt)
#pragma unroll
    for (int g = 0; g < 4; ++g) {
      u32 wa = pack2bf(oacc[dt][4 * g + 0] * inv, oacc[dt][4 * g + 1] * inv);
      u32 wb = pack2bf(oacc[dt][4 * g + 2] * inv, oacc[dt][4 * g + 3] * inv);
      u32x2 pr; pr[0] = wa; pr[1] = wb;
      *(u32x2*)&orow[dt * 32 + g * 8] = pr;
    }
}

extern "C" void kernel_launch(void* const* d_in, const int* in_sizes, int n_in,
                              void* d_out, int out_size, void* d_ws, size_t ws_size,
                              hipStream_t stream) {
  const float* x      = (const float*)d_in[0];
  const float* w_qkv  = (const float*)d_in[1];
  const float* b_qkv  = (const float*)d_in[2];
  const float* w_proj = (const float*)d_in[3];
  const float* b_proj = (const float*)d_in[4];

  u16* ws = (u16*)d_ws;
  u16* xbf    = ws;                      // 25165824 elems (aliased as attn_o after QKV GEMM)
  u16* attn_o = xbf;
  u16* wqkvT  = ws + 25165824;           // 1769472
  u16* wprojT = wqkvT + 1769472;         // 589824
  u16* qkvb   = wprojT + 589824;         // 75497472
  u16* vtb    = qkvb + 75497472;         // 25165824

  k_convert<<<2048, 256, 0, stream>>>(x, xbf, 25165824 / 4);
  k_transpose<<<dim3(2304 / 32, 768 / 32), dim3(32, 8), 0, stream>>>(w_qkv, wqkvT, 768, 2304);
  k_transpose<<<dim3(768 / 32, 768 / 32), dim3(32, 8), 0, stream>>>(w_proj, wprojT, 768, 768);
  k_gemm<0><<<18 * 256, 256, 0, stream>>>(xbf, wqkvT, b_qkv, qkvb, 2304, 18);
  k_vtrans<<<dim3(16, 384), 256, 0, stream>>>(qkvb, vtb);
  k_attn<<<3072, 256, 0, stream>>>(qkvb, vtb, attn_o);
  k_gemm<1><<<6 * 256, 256, 0, stream>>>(attn_o, wprojT, b_proj, d_out, 768, 6);
}